// Round 9
// baseline (4536.147 us; speedup 1.0000x reference)
//
#include <hip/hip_runtime.h>
#include <cstdint>
#include <cstddef>

// Problem constants (fixed by reference setup_inputs)
constexpr int Bb = 8;
constexpr int Nn = 8192;
constexpr int Ss = 2048;
constexpr int BS = Bb * Ss;  // 16384
constexpr int NSL = 32;      // BN-stat atomic stripe count

typedef float vfloat2 __attribute__((ext_vector_type(2)));

// Producer-consumer control block (agent-scope atomics; zeroed each launch).
struct Ctl {
  int prog[8];     // centers published per batch (release by fps producers)
  int pad0[24];
  unsigned role; int padr[31];  // role claim counter (first 8 claimers = fps)
  unsigned tq0; int p1[31];     // ballq tickets
  unsigned tq1; int p2[31];     // L1-s0 tickets
  unsigned tq2; int p3[31];     // L1-s1 tickets
  int flag[1024];  // ballq 16-center-group done flags
};

// ---------------------------------------------------------------------------
// Ball query for ONE center, executed by one wave (r12 body, proven).
// ---------------------------------------------------------------------------
__device__ __forceinline__ void ballq_center(const int bs, const int lane,
                                             const float* __restrict__ xyz,
                                             const float* __restrict__ nxyz,
                                             int* __restrict__ idx0,
                                             int* __restrict__ idx1) {
  const int b = bs >> 11;  // S = 2048
  const float* xb = xyz + (size_t)b * Nn * 3;
  const float cxf = nxyz[bs * 3 + 0];
  const float cyf = nxyz[bs * 3 + 1];
  const float czf = nxyz[bs * 3 + 2];
  const double R0d = 0.4 * 0.4, R1d = 0.8 * 0.8;   // exact doubles
  const float R0lo = 0.16f * (1.0f - 1e-5f), R0hi = 0.16f * (1.0f + 1e-5f);
  const float R1lo = 0.64f * (1.0f - 1e-5f), R1hi = 0.64f * (1.0f + 1e-5f);
  int cnt0 = 0, cnt1 = 0, first0 = 0, first1 = 0;
  const unsigned long long lmask = (1ull << lane) - 1ull;
  for (int base = 0; base < Nn; base += 64) {
    const int p = base + lane;
    const float pxs = xb[p * 3 + 0], pys = xb[p * 3 + 1], pzs = xb[p * 3 + 2];
    const float dxf = pxs - cxf, dyf = pys - cyf, dzf = pzs - czf;
    const float d2f = fmaf(dxf, dxf, fmaf(dyf, dyf, dzf * dzf));
    bool in0, in1;
    if (d2f < R0lo) in0 = true;
    else if (d2f > R0hi) in0 = false;
    else {  // certified band: exact f64 (rare)
      double dx = __dsub_rn((double)pxs, (double)cxf);
      double dy = __dsub_rn((double)pys, (double)cyf);
      double dz = __dsub_rn((double)pzs, (double)czf);
      double d2 = __dadd_rn(__dadd_rn(__dmul_rn(dx, dx), __dmul_rn(dy, dy)), __dmul_rn(dz, dz));
      in0 = d2 < R0d;
    }
    if (d2f < R1lo) in1 = true;
    else if (d2f > R1hi) in1 = false;
    else {
      double dx = __dsub_rn((double)pxs, (double)cxf);
      double dy = __dsub_rn((double)pys, (double)cyf);
      double dz = __dsub_rn((double)pzs, (double)czf);
      double d2 = __dadd_rn(__dadd_rn(__dmul_rn(dx, dx), __dmul_rn(dy, dy)), __dmul_rn(dz, dz));
      in1 = d2 < R1d;
    }
    unsigned long long m0 = __ballot(in0);
    unsigned long long m1 = __ballot(in1);
    if (cnt0 < 16 && m0) {
      if (cnt0 == 0) first0 = base + __builtin_ctzll(m0);
      int r = (int)__popcll(m0 & lmask);
      if (in0 && cnt0 + r < 16) idx0[bs * 16 + cnt0 + r] = p;
      cnt0 += (int)__popcll(m0);
    }
    if (cnt1 < 32 && m1) {
      if (cnt1 == 0) first1 = base + __builtin_ctzll(m1);
      int r = (int)__popcll(m1 & lmask);
      if (in1 && cnt1 + r < 32) idx1[bs * 32 + cnt1 + r] = p;
      cnt1 += (int)__popcll(m1);
    }
    if (cnt0 >= 16 && cnt1 >= 32) break;
  }
  const int f0 = cnt0 < 16 ? cnt0 : 16;
  for (int j = f0 + lane; j < 16; j += 64) idx0[bs * 16 + j] = first0;
  const int f1 = cnt1 < 32 ? cnt1 : 32;
  for (int j = f1 + lane; j < 32; j += 64) idx1[bs * 32 + j] = first1;
}

// ---------------------------------------------------------------------------
// Mega kernel, round-23. r22 refuted the fence theory (4x fewer fences ->
// mega unchanged 3040): the +546us producer slowdown is DVFS — with all
// 256 CUs awake the sustained clock drops ~20% (2494 x 1.2 = 2993) and the
// latency-bound fps chain scales 1:1 with clock. This round: GRID 64 (8
// claimed producers + 56 consumers; 192 CUs stay clock-gated). Consumer
// work (~123 CU-ms) still fits under fps's ~2.6ms shadow at 56 CUs
// (~146 CU-ms available). One-variable probe: if mega recovers to ~2600,
// DVFS scales with active CUs; if it stays ~3000, any multi-CU launch
// throttles and overlap is structurally dead -> revert to serial r16.
// Producer fps loop internals byte-identical to the 10-variant floor.
// ---------------------------------------------------------------------------
__global__ __launch_bounds__(1024) void mega_kernel(
    const float* __restrict__ xyz, const float* __restrict__ feats,
    const float* __restrict__ w00, const float* __restrict__ w10,
    float* __restrict__ new_xyz, int* __restrict__ idx0, int* __restrict__ idx1,
    float* __restrict__ hA0, float* __restrict__ hA1,
    float* __restrict__ st0, float* __restrict__ st1, Ctl* ctl) {
  __shared__ __align__(16) unsigned char SM[107008];
  __shared__ int sRole;
  const int tid = threadIdx.x;

  if (tid == 0)
    sRole = (int)__hip_atomic_fetch_add(&ctl->role, 1u, __ATOMIC_RELAXED,
                                        __HIP_MEMORY_SCOPE_AGENT);
  __syncthreads();
  const int role = sRole;

  if (role < 8) {
    // ======================= FPS producer role =======================
    float* lx = (float*)SM;                               // 96 KB
    int* sidx = (int*)(SM + 98304);                       // 8 KB
    unsigned long long* slotV = (unsigned long long*)(SM + 106496);
    int* slotI = (int*)(SM + 106512);
    const int b = role;
    const float* xb = xyz + (size_t)b * Nn * 3;
    float* nxb = new_xyz + (size_t)b * Ss * 3;
    for (int e = tid; e < Nn * 3; e += 1024) lx[e] = xb[e];
    if (tid == 0) {
      slotV[0] = 0ull; slotV[1] = 0ull;
      slotI[0] = 0x7fffffff; slotI[1] = 0x7fffffff;
    }
    __syncthreads();

    vfloat2 px2[4], py2[4], pz2[4], df2[4];
    double dist[8];
#pragma unroll
    for (int jj = 0; jj < 4; ++jj) {
      const int p0 = tid + (2 * jj) * 1024, p1 = tid + (2 * jj + 1) * 1024;
      px2[jj] = (vfloat2){lx[p0 * 3 + 0], lx[p1 * 3 + 0]};
      py2[jj] = (vfloat2){lx[p0 * 3 + 1], lx[p1 * 3 + 1]};
      pz2[jj] = (vfloat2){lx[p0 * 3 + 2], lx[p1 * 3 + 2]};
      df2[jj] = (vfloat2){3.0e38f, 3.0e38f};
      dist[2 * jj] = 1e10;
      dist[2 * jj + 1] = 1e10;
    }
    float lmax = 3.0e38f;
    int cur = 0;
    double lv = -1.0;
    int li = 0x7fffffff;
    float lv32 = -1.0f;
    float wv32_c = -1.0f;
    for (int i = 0; i < Ss; ++i) {
      if (tid == 0) sidx[i] = cur;
      const float cxf = lx[cur * 3 + 0], cyf = lx[cur * 3 + 1], czf = lx[cur * 3 + 2];
      const vfloat2 cx2 = {cxf, cxf}, cy2 = {cyf, cyf}, cz2 = {czf, czf};
      const bool wasTop = (lv32 == wv32_c);
      vfloat2 d2v[4];
#pragma unroll
      for (int jj = 0; jj < 4; ++jj) {
        const vfloat2 dx = px2[jj] - cx2;
        const vfloat2 dy = py2[jj] - cy2;
        const vfloat2 dz = pz2[jj] - cz2;
        d2v[jj] = dx * dx + dy * dy + dz * dz;
      }
      const float dmin = fminf(fminf(fminf(d2v[0].x, d2v[0].y), fminf(d2v[1].x, d2v[1].y)),
                               fminf(fminf(d2v[2].x, d2v[2].y), fminf(d2v[3].x, d2v[3].y)));
      bool changed = false;
      if (dmin <= lmax) {
#pragma unroll
        for (int j = 0; j < 8; ++j) {
          const float d2s = d2v[j >> 1][j & 1];
          const float dfs = (j & 1) ? df2[j >> 1].y : df2[j >> 1].x;
          if (d2s <= dfs) {
            const float pxs = px2[j >> 1][j & 1];
            const float pys = py2[j >> 1][j & 1];
            const float pzs = pz2[j >> 1][j & 1];
            double dx = __dsub_rn((double)pxs, (double)cxf);
            double dy = __dsub_rn((double)pys, (double)cyf);
            double dz = __dsub_rn((double)pzs, (double)czf);
            double d = __dadd_rn(__dadd_rn(__dmul_rn(dx, dx), __dmul_rn(dy, dy)),
                                 __dmul_rn(dz, dz));
            if (d < dist[j]) {
              dist[j] = d;
              const float dfn = (float)d * 1.000002f;
              if (j & 1) df2[j >> 1].y = dfn; else df2[j >> 1].x = dfn;
              changed = true;
            }
          }
        }
        if (changed) {
          lv = -1.0;
          li = 0;
#pragma unroll
          for (int j = 0; j < 8; ++j) {
            if (dist[j] > lv) { lv = dist[j]; li = tid + j * 1024; }
          }
          lv32 = (float)lv;
          lmax = fmaxf(fmaxf(fmaxf(df2[0].x, df2[0].y), fmaxf(df2[1].x, df2[1].y)),
                       fmaxf(fmaxf(df2[2].x, df2[2].y), fmaxf(df2[3].x, df2[3].y)));
        }
      }
      const unsigned long long topChanged = __ballot(changed && wasTop);
      if (topChanged) {
        float m32 = lv32;
#pragma unroll
        for (int off = 1; off < 64; off <<= 1) m32 = fmaxf(m32, __shfl_xor(m32, off));
        wv32_c = m32;
      }
      const int pb = i & 1;
      if (lv32 == wv32_c) atomicMax(&slotV[pb], (unsigned long long)__double_as_longlong(lv));
      __syncthreads();
      const double W = __longlong_as_double((long long)slotV[pb]);
      if (lv == W) atomicMin(&slotI[pb], li);
      if (tid == 0) {
        slotV[pb ^ 1] = 0ull;
        slotI[pb ^ 1] = 0x7fffffff;
      }
      __syncthreads();
      cur = slotI[pb];
      // ---- chunked publication: centers [i-255, i] -> global, release prog
      if ((i & 255) == 255) {
        const int base = i - 255;
        for (int e = tid; e < 768; e += 1024) {
          const int ci = base + e / 3, c = e - (e / 3) * 3;
          nxb[ci * 3 + c] = lx[sidx[ci] * 3 + c];
        }
        __threadfence();
        __syncthreads();
        if (tid == 0)
          __hip_atomic_store(&ctl->prog[b], i + 1, __ATOMIC_RELEASE, __HIP_MEMORY_SCOPE_AGENT);
      }
    }
    return;
  }

  // ======================= consumer role =======================
  float* wS = (float*)SM;                       // [68][64]
  float* xSall = (float*)(SM + 17408);          // 4 x [64][68]
  int* rowPall = (int*)(SM + 87040);            // 4 x 64
  float* rowCall = (float*)(SM + 88064);        // 4 x 192
  int* sTick = (int*)(SM + 91136);
  const int vtid = tid & 255, sub = tid >> 8;
  const int cg = vtid & 15, rg = vtid >> 4;
  float* xS = xSall + sub * (64 * 68);
  int* rP = rowPall + sub * 64;
  float* rC = rowCall + sub * 192;
  const int wid = tid >> 6, lane = tid & 63;

  // ---- phase A: ball query (16 centers per ticket, one wave per center) ----
  for (;;) {
    __syncthreads();
    if (tid == 0) *sTick = (int)atomicAdd(&ctl->tq0, 1u);
    __syncthreads();
    const int t = *sTick;
    if (t >= 1024) break;
    const int b = t & 7, gL = t >> 3;
    if (tid == 0) {
      // terminates: prog[b] advanced by a claimed (= running) producer block
      while (__hip_atomic_load(&ctl->prog[b], __ATOMIC_RELAXED, __HIP_MEMORY_SCOPE_AGENT) <
             gL * 16 + 16)
        __builtin_amdgcn_s_sleep(64);
    }
    __syncthreads();
    (void)__hip_atomic_load(&ctl->prog[b], __ATOMIC_ACQUIRE, __HIP_MEMORY_SCOPE_AGENT);
    ballq_center(b * 2048 + gL * 16 + wid, lane, xyz, new_xyz, idx0, idx1);
    __threadfence();
    __syncthreads();
    if (tid == 0)
      __hip_atomic_store(&ctl->flag[t], 1, __ATOMIC_RELEASE, __HIP_MEMORY_SCOPE_AGENT);
  }

  // ---- phases B/C: MODE0 L1 gather-GEMM (r16 math verbatim per 64-row tile)
  for (int phase = 0; phase < 2; ++phase) {
    const float* wsrc = phase ? w10 : w00;
    const int* gidx = phase ? idx1 : idx0;
    float* Sout = phase ? st1 : st0;
    float* out = phase ? hA1 : hA0;
    const int log2ns = phase ? 5 : 4;
    const int NT = phase ? 2048 : 1024;
    unsigned* tq = phase ? &ctl->tq2 : &ctl->tq1;
    __syncthreads();
    for (int e = tid; e < 68 * 64; e += 1024) {
      const int kk = e >> 6, c = e & 63;
      wS[e] = (kk < 67) ? wsrc[kk * 64 + c] : 0.f;
    }
    for (;;) {
      __syncthreads();
      if (tid == 0) *sTick = (int)atomicAdd(tq, 1u);
      __syncthreads();
      const int v = *sTick;
      if (v >= NT) break;
      const int b = v & 7, j = v >> 3;
      const int u = (phase ? b * 256 : b * 128) + j;          // task id
      const int fIdx = ((phase ? (j >> 1) : j) << 3) | b;     // ballq flag
      if (tid == 0) {
        // terminates: flag set by the running block that pulled ticket fIdx
        while (!__hip_atomic_load(&ctl->flag[fIdx], __ATOMIC_RELAXED, __HIP_MEMORY_SCOPE_AGENT))
          __builtin_amdgcn_s_sleep(64);
      }
      __syncthreads();
      (void)__hip_atomic_load(&ctl->flag[fIdx], __ATOMIC_ACQUIRE, __HIP_MEMORY_SCOPE_AGENT);
      const int g = 4 * u + sub;                              // tile (= old blockIdx)
      const int row0 = g * 64;
      if (vtid < 64) {
        const int rowg = row0 + vtid;
        const int bs = rowg >> log2ns;
        const int bb = bs >> 11;
        rP[vtid] = (bb << 13) + gidx[rowg];
        rC[vtid * 3 + 0] = new_xyz[bs * 3 + 0];
        rC[vtid * 3 + 1] = new_xyz[bs * 3 + 1];
        rC[vtid * 3 + 2] = new_xyz[bs * 3 + 2];
      }
      __syncthreads();
      for (int e = vtid; e < 64 * 68; e += 256) {
        const int r = e / 68, kk = e - r * 68;
        float val;
        if (kk >= 67) val = 0.f;
        else if (kk < 3) val = xyz[rP[r] * 3 + kk] - rC[r * 3 + kk];
        else val = feats[(rP[r] << 6) + (kk - 3)];
        xS[r * 68 + kk] = val;
      }
      __syncthreads();
      vfloat2 acc2[4][2];
#pragma unroll
      for (int i = 0; i < 4; ++i) {
        acc2[i][0] = (vfloat2){0.f, 0.f};
        acc2[i][1] = (vfloat2){0.f, 0.f};
      }
      for (int kb = 0; kb < 68; kb += 4) {
        float4 xv[4];
#pragma unroll
        for (int i = 0; i < 4; ++i)
          xv[i] = *(const float4*)&xS[(rg * 4 + i) * 68 + kb];
        const float4 wv0 = *(const float4*)&wS[(kb + 0) * 64 + cg * 4];
        const float4 wv1 = *(const float4*)&wS[(kb + 1) * 64 + cg * 4];
        const float4 wv2 = *(const float4*)&wS[(kb + 2) * 64 + cg * 4];
        const float4 wv3 = *(const float4*)&wS[(kb + 3) * 64 + cg * 4];
#pragma unroll
        for (int i = 0; i < 4; ++i) {
          { const vfloat2 x2 = {xv[i].x, xv[i].x};
            acc2[i][0] += x2 * (vfloat2){wv0.x, wv0.y};
            acc2[i][1] += x2 * (vfloat2){wv0.z, wv0.w}; }
          { const vfloat2 x2 = {xv[i].y, xv[i].y};
            acc2[i][0] += x2 * (vfloat2){wv1.x, wv1.y};
            acc2[i][1] += x2 * (vfloat2){wv1.z, wv1.w}; }
          { const vfloat2 x2 = {xv[i].z, xv[i].z};
            acc2[i][0] += x2 * (vfloat2){wv2.x, wv2.y};
            acc2[i][1] += x2 * (vfloat2){wv2.z, wv2.w}; }
          { const vfloat2 x2 = {xv[i].w, xv[i].w};
            acc2[i][0] += x2 * (vfloat2){wv3.x, wv3.y};
            acc2[i][1] += x2 * (vfloat2){wv3.z, wv3.w}; }
        }
      }
      __syncthreads();
      float* ssum = xS;            // reuse sub-block scratch
      float* ssq = xS + 1024;
      const int colb = cg * 4;
#pragma unroll
      for (int t = 0; t < 4; ++t) {
        float s = 0.f, q = 0.f;
#pragma unroll
        for (int i = 0; i < 4; ++i) {
          const float val = (t & 1) ? acc2[i][t >> 1].y : acc2[i][t >> 1].x;
          s += val;
          q = fmaf(val, val, q);
        }
        ssum[rg * 64 + colb + t] = s;
        ssq[rg * 64 + colb + t] = q;
      }
      __syncthreads();
      const int slot = g & 31;
      for (int c = vtid; c < 64; c += 256) {
        float s = 0.f, q = 0.f;
#pragma unroll
        for (int rr = 0; rr < 16; ++rr) {
          s += ssum[rr * 64 + c];
          q += ssq[rr * 64 + c];
        }
        atomicAdd(&Sout[c * NSL + slot], s);
        atomicAdd(&Sout[(64 + c) * NSL + slot], q);
      }
#pragma unroll
      for (int i = 0; i < 4; ++i) {
        float* op = out + (size_t)(row0 + rg * 4 + i) * 64 + colb;
        *(float4*)op = make_float4(acc2[i][0].x, acc2[i][0].y, acc2[i][1].x, acc2[i][1].y);
      }
    }
  }
}

// ---------------------------------------------------------------------------
// Standalone ball query (fallback path only). r12, proven.
// ---------------------------------------------------------------------------
__global__ __launch_bounds__(256) void ballq_kernel(const float* __restrict__ xyz,
                                                    const float* __restrict__ nxyz,
                                                    int* __restrict__ idx0,
                                                    int* __restrict__ idx1) {
  const int wid = threadIdx.x >> 6, lane = threadIdx.x & 63;
  ballq_center(blockIdx.x * 4 + wid, lane, xyz, nxyz, idx0, idx1);
}

// ---------------------------------------------------------------------------
// Generic tall-skinny GEMM (r16 K-blocked f32 engine, proven 3671 total).
// MODE 0: gather (rel-xyz ++ features) via ball-query idx          (K=67)
// MODE 1: x = relu(bn(prev_raw)) from 64-ch buffer (in-place safe) (K=64)
// MODE 2: x = concat(relu(bn(pool0)), relu(bn(pool1)))             (K=256)
// MODE 4: x = relu(bn(xin)) from 256-ch buffer; also writes x to hw (K=256)
// ---------------------------------------------------------------------------
template <int COUT, int KTOT, int MODE, int NS, bool POOL, bool BIAS>
__global__ __launch_bounds__(256) void mlp_gemm(
    const float* __restrict__ xin, const float* __restrict__ xin2,
    const float* __restrict__ stIn, const float* __restrict__ stIn2,
    float invM1, float invM2,
    const float* __restrict__ w, const float* __restrict__ bias,
    const int* __restrict__ gidx, const float* __restrict__ xyz,
    const float* __restrict__ nxyz, const float* __restrict__ feats,
    float* __restrict__ hw, float* __restrict__ out, float* __restrict__ Sout) {
  constexpr int KC = (KTOT <= 68) ? KTOT : 32;     // K chunk (real)
  constexpr int KCP = (KC + 3) & ~3;               // padded to mult of 4
  constexpr int NCH = (KTOT + KC - 1) / KC;
  constexpr int TC = COUT / 16;
  constexpr int TC2 = TC / 2;
  constexpr int XPAD = (KCP % 32 == 0) ? KCP + 4 : KCP;
  constexpr int XSZ = 64 * XPAD;
  constexpr int EPI = (POOL ? 48 : 32) * COUT;
  constexpr int SM = (XSZ + KCP * COUT > EPI) ? (XSZ + KCP * COUT) : EPI;
  constexpr int BNSZ = (MODE == 0) ? 0 : 512;
  __shared__ __align__(16) float smem[SM + BNSZ];
  __shared__ int rowP[(MODE == 0) ? 64 : 1];
  __shared__ float rowC[(MODE == 0) ? 192 : 1];
  float* xS = smem;
  float* wS = smem + XSZ;
  float* bnM = smem + SM;
  float* bnR = smem + SM + 256;

  const int tid = threadIdx.x;
  const int cg = tid & 15, rg = tid >> 4;
  const int row0 = blockIdx.x * 64;

  if constexpr (MODE == 0) {
    if (tid < 64) {
      const int rowg = row0 + tid;
      const int bs = rowg / NS;
      const int bb = bs >> 11;
      rowP[tid] = bb * Nn + gidx[rowg];
      rowC[tid * 3 + 0] = nxyz[bs * 3 + 0];
      rowC[tid * 3 + 1] = nxyz[bs * 3 + 1];
      rowC[tid * 3 + 2] = nxyz[bs * 3 + 2];
    }
    __syncthreads();
  } else {
    for (int c = tid; c < KTOT; c += 256) {
      float sum = 0.f, sq = 0.f, im;
      if constexpr (MODE == 2) {
        const float* base = (c < 128) ? stIn : stIn2;
        const int cc = (c < 128) ? c : c - 128;
        im = (c < 128) ? invM1 : invM2;
#pragma unroll
        for (int s = 0; s < NSL; ++s) {
          sum += base[cc * NSL + s];
          sq += base[(128 + cc) * NSL + s];
        }
      } else {
        constexpr int C = (MODE == 1) ? 64 : 256;
        im = invM1;
#pragma unroll
        for (int s = 0; s < NSL; ++s) {
          sum += stIn[c * NSL + s];
          sq += stIn[(C + c) * NSL + s];
        }
      }
      const float mu = sum * im;
      const float var = sq * im - mu * mu;
      bnM[c] = mu;
      bnR[c] = 1.0f / sqrtf(var + 1e-5f);
    }
    __syncthreads();
  }

  vfloat2 acc2[4][TC2];
#pragma unroll
  for (int i = 0; i < 4; ++i)
#pragma unroll
    for (int t = 0; t < TC2; ++t) acc2[i][t] = (vfloat2){0.f, 0.f};

  for (int ch = 0; ch < NCH; ++ch) {
    const int k0 = ch * KC;
    if (ch) __syncthreads();
    for (int e = tid; e < 64 * KCP; e += 256) {
      const int r = e / KCP, kk = e - r * KCP;
      const int kg = k0 + kk;
      const int rowg = row0 + r;
      float v;
      if (kg >= KTOT) {
        v = 0.f;
      } else if constexpr (MODE == 0) {
        if (kg < 3)
          v = xyz[rowP[r] * 3 + kg] - rowC[r * 3 + kg];
        else
          v = feats[(rowP[r] << 6) + (kg - 3)];
      } else if constexpr (MODE == 1) {
        v = fmaxf((xin[(size_t)rowg * 64 + kg] - bnM[kg]) * bnR[kg], 0.f);
      } else if constexpr (MODE == 2) {
        if (kg < 128)
          v = fmaxf((xin[(size_t)rowg * 128 + kg] - bnM[kg]) * bnR[kg], 0.f);
        else
          v = fmaxf((xin2[(size_t)rowg * 128 + (kg - 128)] - bnM[kg]) * bnR[kg], 0.f);
      } else {  // MODE 4
        v = fmaxf((xin[(size_t)rowg * 256 + kg] - bnM[kg]) * bnR[kg], 0.f);
        hw[(size_t)rowg * 256 + kg] = v;
      }
      xS[r * XPAD + kk] = v;
    }
    for (int e = tid; e < KCP * COUT; e += 256) {
      const int kk = e / COUT, c = e - kk * COUT;
      wS[kk * COUT + c] = (k0 + kk < KTOT) ? w[(size_t)(k0 + kk) * COUT + c] : 0.f;
    }
    __syncthreads();
    for (int kb = 0; kb < KCP; kb += 4) {
      float4 xv[4];
#pragma unroll
      for (int i = 0; i < 4; ++i)
        xv[i] = *(const float4*)&xS[(rg * 4 + i) * XPAD + kb];
#pragma unroll
      for (int t2 = 0; t2 < TC2; t2 += 2) {
        float4 wv0 = *(const float4*)&wS[(kb + 0) * COUT + cg * TC + 2 * t2];
        float4 wv1 = *(const float4*)&wS[(kb + 1) * COUT + cg * TC + 2 * t2];
        float4 wv2 = *(const float4*)&wS[(kb + 2) * COUT + cg * TC + 2 * t2];
        float4 wv3 = *(const float4*)&wS[(kb + 3) * COUT + cg * TC + 2 * t2];
#pragma unroll
        for (int i = 0; i < 4; ++i) {
          {
            const vfloat2 x2 = {xv[i].x, xv[i].x};
            acc2[i][t2]     += x2 * (vfloat2){wv0.x, wv0.y};
            acc2[i][t2 + 1] += x2 * (vfloat2){wv0.z, wv0.w};
          }
          {
            const vfloat2 x2 = {xv[i].y, xv[i].y};
            acc2[i][t2]     += x2 * (vfloat2){wv1.x, wv1.y};
            acc2[i][t2 + 1] += x2 * (vfloat2){wv1.z, wv1.w};
          }
          {
            const vfloat2 x2 = {xv[i].z, xv[i].z};
            acc2[i][t2]     += x2 * (vfloat2){wv2.x, wv2.y};
            acc2[i][t2 + 1] += x2 * (vfloat2){wv2.z, wv2.w};
          }
          {
            const vfloat2 x2 = {xv[i].w, xv[i].w};
            acc2[i][t2]     += x2 * (vfloat2){wv3.x, wv3.y};
            acc2[i][t2 + 1] += x2 * (vfloat2){wv3.z, wv3.w};
          }
        }
      }
    }
  }
  __syncthreads();
  if constexpr (BIAS) {
#pragma unroll
    for (int t = 0; t < TC; ++t) {
      const float bv = bias[cg * TC + t];
#pragma unroll
      for (int i = 0; i < 4; ++i) {
        if (t & 1) acc2[i][t >> 1].y += bv; else acc2[i][t >> 1].x += bv;
      }
    }
  }
  float* ssum = smem;
  float* ssq = smem + 16 * COUT;
  float* pbuf = smem + 32 * COUT;
  const int colb = cg * TC;
#pragma unroll
  for (int t = 0; t < TC; ++t) {
    float s = 0.f, q = 0.f, m = -3.4e38f;
#pragma unroll
    for (int i = 0; i < 4; ++i) {
      const float v = (t & 1) ? acc2[i][t >> 1].y : acc2[i][t >> 1].x;
      s += v;
      q = fmaf(v, v, q);
      m = fmaxf(m, v);
    }
    ssum[rg * COUT + colb + t] = s;
    ssq[rg * COUT + colb + t] = q;
    if constexpr (POOL) pbuf[rg * COUT + colb + t] = m;
  }
  __syncthreads();
  const int slot = blockIdx.x & (NSL - 1);
  for (int c = tid; c < COUT; c += 256) {
    float s = 0.f, q = 0.f;
#pragma unroll
    for (int rr = 0; rr < 16; ++rr) {
      s += ssum[rr * COUT + c];
      q += ssq[rr * COUT + c];
    }
    atomicAdd(&Sout[c * NSL + slot], s);
    atomicAdd(&Sout[(COUT + c) * NSL + slot], q);
  }
  if constexpr (POOL) {
    constexpr int G = 64 / NS, RPG = NS / 4;
    for (int o = tid; o < G * COUT; o += 256) {
      const int g = o / COUT, c = o - g * COUT;
      float m = pbuf[(g * RPG) * COUT + c];
#pragma unroll
      for (int qq = 1; qq < RPG; ++qq) m = fmaxf(m, pbuf[(g * RPG + qq) * COUT + c]);
      out[(size_t)(blockIdx.x * G + g) * COUT + c] = m;
    }
  } else {
#pragma unroll
    for (int i = 0; i < 4; ++i) {
      float* op = out + (size_t)(row0 + rg * 4 + i) * COUT + colb;
#pragma unroll
      for (int t2 = 0; t2 < TC2; t2 += 2) {
        *(float4*)(op + 2 * t2) = make_float4(acc2[i][t2].x, acc2[i][t2].y,
                                              acc2[i][t2 + 1].x, acc2[i][t2 + 1].y);
      }
    }
  }
}

// cls = relu(bn(conf_raw)) @ cls_w + cls_b   (one wave per row; inline BN)
__global__ __launch_bounds__(256) void cls_kernel(const float* __restrict__ craw,
                                                  const float* __restrict__ st,
                                                  const float* __restrict__ clsw,
                                                  const float* __restrict__ clsb,
                                                  float* __restrict__ outc) {
  __shared__ float bnM[256], bnR[256];
  const int tid = threadIdx.x;
  {
    float sum = 0.f, sq = 0.f;
#pragma unroll
    for (int s = 0; s < NSL; ++s) {
      sum += st[tid * NSL + s];
      sq += st[(256 + tid) * NSL + s];
    }
    const float im = 1.0f / 16384.0f;
    const float mu = sum * im;
    const float var = sq * im - mu * mu;
    bnM[tid] = mu;
    bnR[tid] = 1.0f / sqrtf(var + 1e-5f);
  }
  __syncthreads();
  const int wid = tid >> 6, lane = tid & 63;
  const int row = blockIdx.x * 4 + wid;
  const float* cr = craw + (size_t)row * 256;
  float a0 = 0.f, a1 = 0.f, a2 = 0.f;
#pragma unroll 4
  for (int k = lane; k < 256; k += 64) {
    float x = fmaxf((cr[k] - bnM[k]) * bnR[k], 0.f);
    a0 = fmaf(x, clsw[k * 3 + 0], a0);
    a1 = fmaf(x, clsw[k * 3 + 1], a1);
    a2 = fmaf(x, clsw[k * 3 + 2], a2);
  }
#pragma unroll
  for (int off = 32; off; off >>= 1) {
    a0 += __shfl_down(a0, off);
    a1 += __shfl_down(a1, off);
    a2 += __shfl_down(a2, off);
  }
  if (lane == 0) {
    outc[row * 3 + 0] = a0 + clsb[0];
    outc[row * 3 + 1] = a1 + clsb[1];
    outc[row * 3 + 2] = a2 + clsb[2];
  }
}

// ---------------------------------------------------------------------------
extern "C" void kernel_launch(void* const* d_in, const int* in_sizes, int n_in,
                              void* d_out, int out_size, void* d_ws, size_t ws_size,
                              hipStream_t stream) {
  (void)in_sizes; (void)n_in; (void)out_size;
  const float* xyz = (const float*)d_in[0];
  const float* feats = (const float*)d_in[1];
  const float* w00 = (const float*)d_in[2];
  const float* w01 = (const float*)d_in[3];
  const float* w02 = (const float*)d_in[4];
  const float* w10 = (const float*)d_in[5];
  const float* w11 = (const float*)d_in[6];
  const float* w12 = (const float*)d_in[7];
  const float* aggw = (const float*)d_in[8];
  const float* aggb = (const float*)d_in[9];
  const float* confw = (const float*)d_in[10];
  const float* clsw = (const float*)d_in[11];
  const float* clsb = (const float*)d_in[12];

  float* outp = (float*)d_out;
  float* nxyz = outp;                               // [BS,3]
  float* hout = outp + (size_t)BS * 3;              // [BS,256]
  float* clsout = hout + (size_t)BS * 256;          // [BS,3]

  char* ws = (char*)d_ws;
  const size_t MB = 1ull << 20;
  int* idx0 = (int*)(ws + 0);                       // 1 MB
  int* idx1 = (int*)(ws + 1 * MB);                  // 2 MB
  Ctl* ctl = (Ctl*)(ws + 3 * MB + 512 * 1024);      // ~4.6 KB (both layouts)
  const bool OV = ws_size >= 217ull * MB;           // overlap layout fits?

  float *st, *pool0, *pool1, *aggraw, *confraw, *hA0, *hA1;
  if (OV) {
    // Overlap layout: s0/s1 L1 outputs coexist.
    st = (float*)(ws + 4 * MB);                     // 256 KB
    pool0 = (float*)(ws + 5 * MB);                  // 8 MB [5,13)
    hA0 = (float*)(ws + 16 * MB);                   // 64 MB [16,80)
    hA1 = (float*)(ws + 83 * MB);                   // 134 MB [83,217)
    pool1 = (float*)(ws + 16 * MB);                 // overlays dead hA0 (post-s0)
    aggraw = (float*)(ws + 24 * MB);                // dead hA0 region
    confraw = (float*)(ws + 40 * MB);               // dead hA0 region
  } else {
    // r16 serial layout (proven).
    st = (float*)(ws + 3 * MB);
    pool0 = (float*)(ws + 12 * MB);
    pool1 = (float*)(ws + 20 * MB);
    aggraw = (float*)(ws + 28 * MB);
    confraw = (float*)(ws + 44 * MB);
    hA0 = (float*)(ws + 60 * MB);
    hA1 = hA0;                                      // serial reuse
  }

  hipMemsetAsync(st, 0, 65536 * sizeof(float), stream);
  hipMemsetAsync(ctl, 0, sizeof(Ctl), stream);

  const float iM0 = 1.0f / 262144.0f;   // scale0 rows
  const float iM1 = 1.0f / 524288.0f;   // scale1 rows
  const float iMh = 1.0f / 16384.0f;    // BS rows

  if (OV) {
    // 8 claimed producers + 56 consumers; 192 CUs stay clock-gated (DVFS probe)
    mega_kernel<<<64, 1024, 0, stream>>>(xyz, feats, w00, w10, nxyz, idx0, idx1,
                                         hA0, hA1, st + 0, st + 16384, ctl);
  } else {
    mega_kernel<<<8, 1024, 0, stream>>>(xyz, feats, w00, w10, nxyz, idx0, idx1,
                                        hA0, hA1, st + 0, st + 16384, ctl);
    ballq_kernel<<<BS / 4, 256, 0, stream>>>(xyz, nxyz, idx0, idx1);
    mlp_gemm<64, 67, 0, 16, false, false><<<4096, 256, 0, stream>>>(
        nullptr, nullptr, nullptr, nullptr, 0.f, 0.f, w00, nullptr,
        idx0, xyz, nxyz, feats, nullptr, hA0, st + 0);
  }

  // ---- scale 0 L2/L3 ----
  mlp_gemm<64, 64, 1, 1, false, false><<<4096, 256, 0, stream>>>(
      hA0, nullptr, st + 0, nullptr, iM0, 0.f, w01, nullptr,
      nullptr, nullptr, nullptr, nullptr, nullptr, hA0, st + 4096);
  mlp_gemm<128, 64, 1, 16, true, false><<<4096, 256, 0, stream>>>(
      hA0, nullptr, st + 4096, nullptr, iM0, 0.f, w02, nullptr,
      nullptr, nullptr, nullptr, nullptr, nullptr, pool0, st + 8192);

  // ---- scale 1 L1 (fallback only; overlapped path did it in mega) ----
  if (!OV) {
    mlp_gemm<64, 67, 0, 32, false, false><<<8192, 256, 0, stream>>>(
        nullptr, nullptr, nullptr, nullptr, 0.f, 0.f, w10, nullptr,
        idx1, xyz, nxyz, feats, nullptr, hA1, st + 16384);
  }
  // ---- scale 1 L2/L3 ----
  mlp_gemm<64, 64, 1, 1, false, false><<<8192, 256, 0, stream>>>(
      hA1, nullptr, st + 16384, nullptr, iM1, 0.f, w11, nullptr,
      nullptr, nullptr, nullptr, nullptr, nullptr, hA1, st + 20480);
  mlp_gemm<128, 64, 1, 32, true, false><<<8192, 256, 0, stream>>>(
      hA1, nullptr, st + 20480, nullptr, iM1, 0.f, w12, nullptr,
      nullptr, nullptr, nullptr, nullptr, nullptr, pool1, st + 24576);

  // ---- aggregation: concat(bn3_0(pool0), bn3_1(pool1)) @ agg_w + agg_b ----
  mlp_gemm<256, 256, 2, 1, false, true><<<256, 256, 0, stream>>>(
      pool0, pool1, st + 8192, st + 24576, iM0, iM1, aggw, aggb,
      nullptr, nullptr, nullptr, nullptr, nullptr, aggraw, st + 32768);

  // ---- confidence hidden layer ----
  mlp_gemm<256, 256, 4, 1, false, false><<<256, 256, 0, stream>>>(
      aggraw, nullptr, st + 32768, nullptr, iMh, 0.f, confw, nullptr,
      nullptr, nullptr, nullptr, nullptr, hout, confraw, st + 49152);

  // ---- classifier ----
  cls_kernel<<<BS / 4, 256, 0, stream>>>(confraw, st + 49152, clsw, clsb, clsout);
}

// Round 11
// 3625.695 us; speedup vs baseline: 1.2511x; 1.2511x over previous
//
#include <hip/hip_runtime.h>
#include <cstdint>
#include <cstddef>

// Problem constants (fixed by reference setup_inputs)
constexpr int Bb = 8;
constexpr int Nn = 8192;
constexpr int Ss = 2048;
constexpr int BS = Bb * Ss;  // 16384
constexpr int NSL = 32;      // BN-stat atomic stripe count

typedef float vfloat2 __attribute__((ext_vector_type(2)));

// ---------------------------------------------------------------------------
// FPS: one block per batch, 1024 threads, 8 points/thread. r12/r16 structure
// VERBATIM — proven 2494-2500 us floor across 10 variants (r14 shuffle-slots,
// r15 coord-keys, r18 512x16, r20-r23 producer variants all regressed).
// The overlap arc (r19-r23) proved co-residency costs ~500us on this
// clock-sensitive chain (> the ~480us absorbable tail) — fps must run ALONE.
// DO NOT modify this kernel.
// ---------------------------------------------------------------------------
__global__ __launch_bounds__(1024) void fps_kernel(const float* __restrict__ xyz,
                                                   float* __restrict__ new_xyz) {
  __shared__ float lx[Nn * 3];             // 96 KB: batch point cloud
  __shared__ int sidx[Ss];                 // 8 KB: selected-index log
  __shared__ unsigned long long slotV[2];  // parity: f64-bit global max
  __shared__ int slotI[2];                 // parity: winner index (min over ties)
  const int b = blockIdx.x;
  const int tid = threadIdx.x;
  const float* xb = xyz + (size_t)b * Nn * 3;
  for (int e = tid; e < Nn * 3; e += 1024) lx[e] = xb[e];
  if (tid == 0) {
    slotV[0] = 0ull; slotV[1] = 0ull;
    slotI[0] = 0x7fffffff; slotI[1] = 0x7fffffff;
  }
  __syncthreads();

  vfloat2 px2[4], py2[4], pz2[4], df2[4];
  double dist[8];
#pragma unroll
  for (int jj = 0; jj < 4; ++jj) {
    const int p0 = tid + (2 * jj) * 1024, p1 = tid + (2 * jj + 1) * 1024;
    px2[jj] = (vfloat2){lx[p0 * 3 + 0], lx[p1 * 3 + 0]};
    py2[jj] = (vfloat2){lx[p0 * 3 + 1], lx[p1 * 3 + 1]};
    pz2[jj] = (vfloat2){lx[p0 * 3 + 2], lx[p1 * 3 + 2]};
    df2[jj] = (vfloat2){3.0e38f, 3.0e38f};   // force exact path on first touch
    dist[2 * jj] = 1e10;
    dist[2 * jj + 1] = 1e10;
  }
  float lmax = 3.0e38f;                    // cached max of certified bounds
  int cur = 0;
  double lv = -1.0;                        // per-lane cached local max (exact)
  int li = 0x7fffffff;
  float lv32 = -1.0f;                      // cached (float)lv
  float wv32_c = -1.0f;                    // cached wave f32 max
  for (int i = 0; i < Ss; ++i) {
    if (tid == 0) sidx[i] = cur;           // LDS log (visible after barrier)
    const float cxf = lx[cur * 3 + 0], cyf = lx[cur * 3 + 1], czf = lx[cur * 3 + 2];
    const vfloat2 cx2 = {cxf, cxf}, cy2 = {cyf, cyf}, cz2 = {czf, czf};
    const bool wasTop = (lv32 == wv32_c);  // latched BEFORE updates
    // ---- packed-f32 distances ----
    vfloat2 d2v[4];
#pragma unroll
    for (int jj = 0; jj < 4; ++jj) {
      const vfloat2 dx = px2[jj] - cx2;
      const vfloat2 dy = py2[jj] - cy2;
      const vfloat2 dz = pz2[jj] - cz2;
      d2v[jj] = dx * dx + dy * dy + dz * dz;
    }
    const float dmin = fminf(fminf(fminf(d2v[0].x, d2v[0].y), fminf(d2v[1].x, d2v[1].y)),
                             fminf(fminf(d2v[2].x, d2v[2].y), fminf(d2v[3].x, d2v[3].y)));
    bool changed = false;
    if (dmin <= lmax) {                    // necessary condition for any update
#pragma unroll
      for (int j = 0; j < 8; ++j) {
        const float d2s = d2v[j >> 1][j & 1];
        const float dfs = (j & 1) ? df2[j >> 1].y : df2[j >> 1].x;
        if (d2s <= dfs) {                  // certified screen -> exact f64
          const float pxs = px2[j >> 1][j & 1];
          const float pys = py2[j >> 1][j & 1];
          const float pzs = pz2[j >> 1][j & 1];
          double dx = __dsub_rn((double)pxs, (double)cxf);
          double dy = __dsub_rn((double)pys, (double)cyf);
          double dz = __dsub_rn((double)pzs, (double)czf);
          double d = __dadd_rn(__dadd_rn(__dmul_rn(dx, dx), __dmul_rn(dy, dy)),
                               __dmul_rn(dz, dz));
          if (d < dist[j]) {
            dist[j] = d;
            const float dfn = (float)d * 1.000002f;  // certified upper bound
            if (j & 1) df2[j >> 1].y = dfn; else df2[j >> 1].x = dfn;
            changed = true;
          }
        }
      }
      if (changed) {                       // rescan local max + refresh lmax
        lv = -1.0;
        li = 0;
#pragma unroll
        for (int j = 0; j < 8; ++j) {
          if (dist[j] > lv) { lv = dist[j]; li = tid + j * 1024; }  // j asc => min idx on tie
        }
        lv32 = (float)lv;
        lmax = fmaxf(fmaxf(fmaxf(df2[0].x, df2[0].y), fmaxf(df2[1].x, df2[1].y)),
                     fmaxf(fmaxf(df2[2].x, df2[2].y), fmaxf(df2[3].x, df2[3].y)));
      }
    }
    // wave f32 max needs recompute only if a former top lane changed
    const unsigned long long topChanged = __ballot(changed && wasTop);
    if (topChanged) {
      float m32 = lv32;
#pragma unroll
      for (int off = 1; off < 64; off <<= 1) m32 = fmaxf(m32, __shfl_xor(m32, off));
      wv32_c = m32;
    }
    const int pb = i & 1;
    // candidate lanes (contain the exact f64 wave max by monotonicity)
    if (lv32 == wv32_c) atomicMax(&slotV[pb], (unsigned long long)__double_as_longlong(lv));
    __syncthreads();
    const double W = __longlong_as_double((long long)slotV[pb]);
    if (lv == W) atomicMin(&slotI[pb], li);
    if (tid == 0) {                        // reset other parity for iter i+1
      slotV[pb ^ 1] = 0ull;
      slotI[pb ^ 1] = 0x7fffffff;
    }
    __syncthreads();
    cur = slotI[pb];
  }
  __syncthreads();
  // final gather: new_xyz[i][c] = lx[sidx[i]*3 + c]
  float* nxb = new_xyz + (size_t)b * Ss * 3;
  for (int e = tid; e < Ss * 3; e += 1024) {
    const int i = e / 3, c = e - i * 3;
    nxb[e] = lx[sidx[i] * 3 + c];
  }
}

// ---------------------------------------------------------------------------
// Ball query, both scales fused. One wave per center. f32 distances with a
// certified band fallback (exact f64 inside the band). r12, proven.
// ---------------------------------------------------------------------------
__global__ __launch_bounds__(256) void ballq_kernel(const float* __restrict__ xyz,
                                                    const float* __restrict__ nxyz,
                                                    int* __restrict__ idx0,
                                                    int* __restrict__ idx1) {
  const int wid = threadIdx.x >> 6, lane = threadIdx.x & 63;
  const int bs = blockIdx.x * 4 + wid;
  const int b = bs >> 11;  // S = 2048
  const float* xb = xyz + (size_t)b * Nn * 3;
  const float cxf = nxyz[bs * 3 + 0];
  const float cyf = nxyz[bs * 3 + 1];
  const float czf = nxyz[bs * 3 + 2];
  const double R0d = 0.4 * 0.4, R1d = 0.8 * 0.8;   // exact doubles
  const float R0lo = 0.16f * (1.0f - 1e-5f), R0hi = 0.16f * (1.0f + 1e-5f);
  const float R1lo = 0.64f * (1.0f - 1e-5f), R1hi = 0.64f * (1.0f + 1e-5f);
  int cnt0 = 0, cnt1 = 0, first0 = 0, first1 = 0;
  const unsigned long long lmask = (1ull << lane) - 1ull;
  for (int base = 0; base < Nn; base += 64) {
    const int p = base + lane;
    const float pxs = xb[p * 3 + 0], pys = xb[p * 3 + 1], pzs = xb[p * 3 + 2];
    const float dxf = pxs - cxf, dyf = pys - cyf, dzf = pzs - czf;
    const float d2f = fmaf(dxf, dxf, fmaf(dyf, dyf, dzf * dzf));
    bool in0, in1;
    if (d2f < R0lo) in0 = true;
    else if (d2f > R0hi) in0 = false;
    else {  // certified band: exact f64 (rare)
      double dx = __dsub_rn((double)pxs, (double)cxf);
      double dy = __dsub_rn((double)pys, (double)cyf);
      double dz = __dsub_rn((double)pzs, (double)czf);
      double d2 = __dadd_rn(__dadd_rn(__dmul_rn(dx, dx), __dmul_rn(dy, dy)), __dmul_rn(dz, dz));
      in0 = d2 < R0d;
    }
    if (d2f < R1lo) in1 = true;
    else if (d2f > R1hi) in1 = false;
    else {
      double dx = __dsub_rn((double)pxs, (double)cxf);
      double dy = __dsub_rn((double)pys, (double)cyf);
      double dz = __dsub_rn((double)pzs, (double)czf);
      double d2 = __dadd_rn(__dadd_rn(__dmul_rn(dx, dx), __dmul_rn(dy, dy)), __dmul_rn(dz, dz));
      in1 = d2 < R1d;
    }
    unsigned long long m0 = __ballot(in0);
    unsigned long long m1 = __ballot(in1);
    if (cnt0 < 16 && m0) {
      if (cnt0 == 0) first0 = base + __builtin_ctzll(m0);
      int r = (int)__popcll(m0 & lmask);
      if (in0 && cnt0 + r < 16) idx0[bs * 16 + cnt0 + r] = p;
      cnt0 += (int)__popcll(m0);
    }
    if (cnt1 < 32 && m1) {
      if (cnt1 == 0) first1 = base + __builtin_ctzll(m1);
      int r = (int)__popcll(m1 & lmask);
      if (in1 && cnt1 + r < 32) idx1[bs * 32 + cnt1 + r] = p;
      cnt1 += (int)__popcll(m1);
    }
    if (cnt0 >= 16 && cnt1 >= 32) break;
  }
  const int f0 = cnt0 < 16 ? cnt0 : 16;
  for (int j = f0 + lane; j < 16; j += 64) idx0[bs * 16 + j] = first0;
  const int f1 = cnt1 < 32 ? cnt1 : 32;
  for (int j = f1 + lane; j < 32; j += 64) idx1[bs * 32 + j] = first1;
}

// ---------------------------------------------------------------------------
// Generic tall-skinny GEMM (r16 K-blocked f32 engine, proven 3671 total).
// Round-25 = r24 resubmit: full audit found no defect (bounds exact on all
// merged accesses; no sync constructs -> no deadlock possible; kernarg 176B;
// POOL-only runtime G/RPG guarded by if-constexpr). r24's "container failed
// twice" attributed to infra flake. MERGED batches the independent s0/s1
// layer pairs into one launch (blocks >= split use the B param set; runtime
// log2ns). Per-tile math, row mapping, stats slot (bid & 31; split=4096 ==
// 0 mod 32) bit-identical to the serial pair — only launch grouping changes.
// MODE 0: gather (rel-xyz ++ features) via ball-query idx          (K=67)
// MODE 1: x = relu(bn(prev_raw)) from 64-ch buffer (in-place safe) (K=64)
// MODE 2: x = concat(relu(bn(pool0)), relu(bn(pool1)))             (K=256)
// MODE 4: x = relu(bn(xin)) from 256-ch buffer; also writes x to hw (K=256)
// ---------------------------------------------------------------------------
template <int COUT, int KTOT, int MODE, int NS, bool POOL, bool BIAS, bool MERGED>
__global__ __launch_bounds__(256) void mlp_gemm(
    const float* __restrict__ xin, const float* __restrict__ xin2,
    const float* __restrict__ stIn, const float* __restrict__ stIn2,
    float invM1, float invM2,
    const float* __restrict__ w, const float* __restrict__ bias,
    const int* __restrict__ gidx, const float* __restrict__ xyz,
    const float* __restrict__ nxyz, const float* __restrict__ feats,
    float* __restrict__ hw, float* __restrict__ out, float* __restrict__ Sout,
    int split, int l2nsA, int l2nsB,
    const float* __restrict__ xinB, const float* __restrict__ stInB, float invMB,
    const float* __restrict__ wB, const int* __restrict__ gidxB,
    float* __restrict__ outB, float* __restrict__ SoutB) {
  constexpr int KC = (KTOT <= 68) ? KTOT : 32;     // K chunk (real)
  constexpr int KCP = (KC + 3) & ~3;               // padded to mult of 4
  constexpr int NCH = (KTOT + KC - 1) / KC;
  constexpr int TC = COUT / 16;
  constexpr int TC2 = TC / 2;
  constexpr int XPAD = (KCP % 32 == 0) ? KCP + 4 : KCP;
  constexpr int XSZ = 64 * XPAD;
  constexpr int EPI = (POOL ? 48 : 32) * COUT;
  constexpr int SM = (XSZ + KCP * COUT > EPI) ? (XSZ + KCP * COUT) : EPI;
  constexpr int BNSZ = (MODE == 0) ? 0 : 512;
  __shared__ __align__(16) float smem[SM + BNSZ];
  __shared__ int rowP[(MODE == 0) ? 64 : 1];
  __shared__ float rowC[(MODE == 0) ? 192 : 1];
  float* xS = smem;
  float* wS = smem + XSZ;
  float* bnM = smem + SM;
  float* bnR = smem + SM + 256;

  const int tid = threadIdx.x;
  const int cg = tid & 15, rg = tid >> 4;

  // ---- MERGED param-set selection (compile-time no-op when !MERGED) ----
  int bid = blockIdx.x;
  const float* xinP = xin;
  const float* stP = stIn;
  float invMP = invM1;
  const float* wP = w;
  const int* gidxP = gidx;
  float* outP = out;
  float* SoutP = Sout;
  int l2ns = l2nsA;
  if constexpr (MERGED) {
    if (blockIdx.x >= split) {
      bid = blockIdx.x - split;
      xinP = xinB; stP = stInB; invMP = invMB; wP = wB; gidxP = gidxB;
      outP = outB; SoutP = SoutB; l2ns = l2nsB;
    }
  }
  const int row0 = bid * 64;

  if constexpr (MODE == 0) {
    if (tid < 64) {
      const int rowg = row0 + tid;
      const int bs = MERGED ? (rowg >> l2ns) : (rowg / NS);
      const int bb = bs >> 11;
      rowP[tid] = bb * Nn + gidxP[rowg];
      rowC[tid * 3 + 0] = nxyz[bs * 3 + 0];
      rowC[tid * 3 + 1] = nxyz[bs * 3 + 1];
      rowC[tid * 3 + 2] = nxyz[bs * 3 + 2];
    }
    __syncthreads();
  } else {
    for (int c = tid; c < KTOT; c += 256) {
      float sum = 0.f, sq = 0.f, im;
      if constexpr (MODE == 2) {
        const float* base = (c < 128) ? stIn : stIn2;
        const int cc = (c < 128) ? c : c - 128;
        im = (c < 128) ? invM1 : invM2;
#pragma unroll
        for (int s = 0; s < NSL; ++s) {
          sum += base[cc * NSL + s];
          sq += base[(128 + cc) * NSL + s];
        }
      } else {
        constexpr int C = (MODE == 1) ? 64 : 256;
        im = invMP;
#pragma unroll
        for (int s = 0; s < NSL; ++s) {
          sum += stP[c * NSL + s];
          sq += stP[(C + c) * NSL + s];
        }
      }
      const float mu = sum * im;
      const float var = sq * im - mu * mu;
      bnM[c] = mu;
      bnR[c] = 1.0f / sqrtf(var + 1e-5f);
    }
    __syncthreads();
  }

  vfloat2 acc2[4][TC2];
#pragma unroll
  for (int i = 0; i < 4; ++i)
#pragma unroll
    for (int t = 0; t < TC2; ++t) acc2[i][t] = (vfloat2){0.f, 0.f};

  for (int ch = 0; ch < NCH; ++ch) {
    const int k0 = ch * KC;
    if (ch) __syncthreads();
    for (int e = tid; e < 64 * KCP; e += 256) {
      const int r = e / KCP, kk = e - r * KCP;
      const int kg = k0 + kk;
      const int rowg = row0 + r;
      float v;
      if (kg >= KTOT) {
        v = 0.f;
      } else if constexpr (MODE == 0) {
        if (kg < 3)
          v = xyz[rowP[r] * 3 + kg] - rowC[r * 3 + kg];
        else
          v = feats[(rowP[r] << 6) + (kg - 3)];
      } else if constexpr (MODE == 1) {
        v = fmaxf((xinP[(size_t)rowg * 64 + kg] - bnM[kg]) * bnR[kg], 0.f);
      } else if constexpr (MODE == 2) {
        if (kg < 128)
          v = fmaxf((xin[(size_t)rowg * 128 + kg] - bnM[kg]) * bnR[kg], 0.f);
        else
          v = fmaxf((xin2[(size_t)rowg * 128 + (kg - 128)] - bnM[kg]) * bnR[kg], 0.f);
      } else {  // MODE 4
        v = fmaxf((xinP[(size_t)rowg * 256 + kg] - bnM[kg]) * bnR[kg], 0.f);
        hw[(size_t)rowg * 256 + kg] = v;
      }
      xS[r * XPAD + kk] = v;
    }
    for (int e = tid; e < KCP * COUT; e += 256) {
      const int kk = e / COUT, c = e - kk * COUT;
      wS[kk * COUT + c] = (k0 + kk < KTOT) ? wP[(size_t)(k0 + kk) * COUT + c] : 0.f;
    }
    __syncthreads();
    for (int kb = 0; kb < KCP; kb += 4) {
      float4 xv[4];
#pragma unroll
      for (int i = 0; i < 4; ++i)
        xv[i] = *(const float4*)&xS[(rg * 4 + i) * XPAD + kb];
#pragma unroll
      for (int t2 = 0; t2 < TC2; t2 += 2) {
        float4 wv0 = *(const float4*)&wS[(kb + 0) * COUT + cg * TC + 2 * t2];
        float4 wv1 = *(const float4*)&wS[(kb + 1) * COUT + cg * TC + 2 * t2];
        float4 wv2 = *(const float4*)&wS[(kb + 2) * COUT + cg * TC + 2 * t2];
        float4 wv3 = *(const float4*)&wS[(kb + 3) * COUT + cg * TC + 2 * t2];
#pragma unroll
        for (int i = 0; i < 4; ++i) {
          {
            const vfloat2 x2 = {xv[i].x, xv[i].x};
            acc2[i][t2]     += x2 * (vfloat2){wv0.x, wv0.y};
            acc2[i][t2 + 1] += x2 * (vfloat2){wv0.z, wv0.w};
          }
          {
            const vfloat2 x2 = {xv[i].y, xv[i].y};
            acc2[i][t2]     += x2 * (vfloat2){wv1.x, wv1.y};
            acc2[i][t2 + 1] += x2 * (vfloat2){wv1.z, wv1.w};
          }
          {
            const vfloat2 x2 = {xv[i].z, xv[i].z};
            acc2[i][t2]     += x2 * (vfloat2){wv2.x, wv2.y};
            acc2[i][t2 + 1] += x2 * (vfloat2){wv2.z, wv2.w};
          }
          {
            const vfloat2 x2 = {xv[i].w, xv[i].w};
            acc2[i][t2]     += x2 * (vfloat2){wv3.x, wv3.y};
            acc2[i][t2 + 1] += x2 * (vfloat2){wv3.z, wv3.w};
          }
        }
      }
    }
  }
  __syncthreads();
  if constexpr (BIAS) {
#pragma unroll
    for (int t = 0; t < TC; ++t) {
      const float bv = bias[cg * TC + t];
#pragma unroll
      for (int i = 0; i < 4; ++i) {
        if (t & 1) acc2[i][t >> 1].y += bv; else acc2[i][t >> 1].x += bv;
      }
    }
  }
  float* ssum = smem;
  float* ssq = smem + 16 * COUT;
  float* pbuf = smem + 32 * COUT;
  const int colb = cg * TC;
#pragma unroll
  for (int t = 0; t < TC; ++t) {
    float s = 0.f, q = 0.f, m = -3.4e38f;
#pragma unroll
    for (int i = 0; i < 4; ++i) {
      const float v = (t & 1) ? acc2[i][t >> 1].y : acc2[i][t >> 1].x;
      s += v;
      q = fmaf(v, v, q);
      m = fmaxf(m, v);
    }
    ssum[rg * COUT + colb + t] = s;
    ssq[rg * COUT + colb + t] = q;
    if constexpr (POOL) pbuf[rg * COUT + colb + t] = m;
  }
  __syncthreads();
  const int slot = bid & (NSL - 1);
  for (int c = tid; c < COUT; c += 256) {
    float s = 0.f, q = 0.f;
#pragma unroll
    for (int rr = 0; rr < 16; ++rr) {
      s += ssum[rr * COUT + c];
      q += ssq[rr * COUT + c];
    }
    atomicAdd(&SoutP[c * NSL + slot], s);
    atomicAdd(&SoutP[(COUT + c) * NSL + slot], q);
  }
  if constexpr (POOL) {
    constexpr int Gc = 64 / NS, RPGc = NS / 4;
    const int G = MERGED ? (64 >> l2ns) : Gc;
    const int RPG = MERGED ? (1 << (l2ns - 2)) : RPGc;
    for (int o = tid; o < G * COUT; o += 256) {
      const int g = o / COUT, c = o - g * COUT;
      float m = pbuf[(g * RPG) * COUT + c];
      for (int qq = 1; qq < RPG; ++qq) m = fmaxf(m, pbuf[(g * RPG + qq) * COUT + c]);
      outP[(size_t)(bid * G + g) * COUT + c] = m;
    }
  } else {
#pragma unroll
    for (int i = 0; i < 4; ++i) {
      float* op = outP + (size_t)(row0 + rg * 4 + i) * COUT + colb;
#pragma unroll
      for (int t2 = 0; t2 < TC2; t2 += 2) {
        *(float4*)(op + 2 * t2) = make_float4(acc2[i][t2].x, acc2[i][t2].y,
                                              acc2[i][t2 + 1].x, acc2[i][t2 + 1].y);
      }
    }
  }
}

// cls = relu(bn(conf_raw)) @ cls_w + cls_b   (one wave per row; inline BN)
__global__ __launch_bounds__(256) void cls_kernel(const float* __restrict__ craw,
                                                  const float* __restrict__ st,
                                                  const float* __restrict__ clsw,
                                                  const float* __restrict__ clsb,
                                                  float* __restrict__ outc) {
  __shared__ float bnM[256], bnR[256];
  const int tid = threadIdx.x;
  {
    float sum = 0.f, sq = 0.f;
#pragma unroll
    for (int s = 0; s < NSL; ++s) {
      sum += st[tid * NSL + s];
      sq += st[(256 + tid) * NSL + s];
    }
    const float im = 1.0f / 16384.0f;
    const float mu = sum * im;
    const float var = sq * im - mu * mu;
    bnM[tid] = mu;
    bnR[tid] = 1.0f / sqrtf(var + 1e-5f);
  }
  __syncthreads();
  const int wid = tid >> 6, lane = tid & 63;
  const int row = blockIdx.x * 4 + wid;
  const float* cr = craw + (size_t)row * 256;
  float a0 = 0.f, a1 = 0.f, a2 = 0.f;
#pragma unroll 4
  for (int k = lane; k < 256; k += 64) {
    float x = fmaxf((cr[k] - bnM[k]) * bnR[k], 0.f);
    a0 = fmaf(x, clsw[k * 3 + 0], a0);
    a1 = fmaf(x, clsw[k * 3 + 1], a1);
    a2 = fmaf(x, clsw[k * 3 + 2], a2);
  }
#pragma unroll
  for (int off = 32; off; off >>= 1) {
    a0 += __shfl_down(a0, off);
    a1 += __shfl_down(a1, off);
    a2 += __shfl_down(a2, off);
  }
  if (lane == 0) {
    outc[row * 3 + 0] = a0 + clsb[0];
    outc[row * 3 + 1] = a1 + clsb[1];
    outc[row * 3 + 2] = a2 + clsb[2];
  }
}

#define NOMERGE 0x40000000, 0, 0, nullptr, nullptr, 0.f, nullptr, nullptr, nullptr, nullptr

// ---------------------------------------------------------------------------
extern "C" void kernel_launch(void* const* d_in, const int* in_sizes, int n_in,
                              void* d_out, int out_size, void* d_ws, size_t ws_size,
                              hipStream_t stream) {
  (void)in_sizes; (void)n_in; (void)out_size;
  const float* xyz = (const float*)d_in[0];
  const float* feats = (const float*)d_in[1];
  const float* w00 = (const float*)d_in[2];
  const float* w01 = (const float*)d_in[3];
  const float* w02 = (const float*)d_in[4];
  const float* w10 = (const float*)d_in[5];
  const float* w11 = (const float*)d_in[6];
  const float* w12 = (const float*)d_in[7];
  const float* aggw = (const float*)d_in[8];
  const float* aggb = (const float*)d_in[9];
  const float* confw = (const float*)d_in[10];
  const float* clsw = (const float*)d_in[11];
  const float* clsb = (const float*)d_in[12];

  float* outp = (float*)d_out;
  float* nxyz = outp;                               // [BS,3]
  float* hout = outp + (size_t)BS * 3;              // [BS,256]
  float* clsout = hout + (size_t)BS * 256;          // [BS,3]

  char* ws = (char*)d_ws;
  const size_t MB = 1ull << 20;
  int* idx0 = (int*)(ws + 0);                       // 1 MB
  int* idx1 = (int*)(ws + 1 * MB);                  // 2 MB
  const bool MG = ws_size >= 217ull * MB;           // merged layout fits?

  float *st, *pool0, *pool1, *aggraw, *confraw, *hA0, *hA1;
  if (MG) {
    // Merged layout: s0/s1 L1 outputs coexist (max offset 216 MB).
    st = (float*)(ws + 4 * MB);                     // 256 KB
    pool0 = (float*)(ws + 5 * MB);                  // 8 MB  [5,13)
    pool1 = (float*)(ws + 13 * MB);                 // 8 MB  [13,21)
    hA0 = (float*)(ws + 24 * MB);                   // 64 MB [24,88)
    hA1 = (float*)(ws + 88 * MB);                   // 128 MB [88,216)
    aggraw = (float*)(ws + 24 * MB);                // reuses dead hA0 (post-L3)
    confraw = (float*)(ws + 40 * MB);               // dead hA0 region
  } else {
    // r16 serial layout (proven fallback).
    st = (float*)(ws + 3 * MB);
    pool0 = (float*)(ws + 12 * MB);
    pool1 = (float*)(ws + 20 * MB);
    aggraw = (float*)(ws + 28 * MB);
    confraw = (float*)(ws + 44 * MB);
    hA0 = (float*)(ws + 60 * MB);
    hA1 = hA0;                                      // serial reuse
  }

  hipMemsetAsync(st, 0, 65536 * sizeof(float), stream);

  const float iM0 = 1.0f / 262144.0f;   // scale0 rows
  const float iM1 = 1.0f / 524288.0f;   // scale1 rows
  const float iMh = 1.0f / 16384.0f;    // BS rows

  fps_kernel<<<Bb, 1024, 0, stream>>>(xyz, nxyz);
  ballq_kernel<<<BS / 4, 256, 0, stream>>>(xyz, nxyz, idx0, idx1);

  if (MG) {
    // ---- merged L1 (s0: 4096 tiles + s1: 8192 tiles) ----
    mlp_gemm<64, 67, 0, 16, false, false, true><<<12288, 256, 0, stream>>>(
        nullptr, nullptr, nullptr, nullptr, 0.f, 0.f, w00, nullptr,
        idx0, xyz, nxyz, feats, nullptr, hA0, st + 0,
        4096, 4, 5, nullptr, nullptr, 0.f, w10, idx1, hA1, st + 16384);
    // ---- merged L2 ----
    mlp_gemm<64, 64, 1, 1, false, false, true><<<12288, 256, 0, stream>>>(
        hA0, nullptr, st + 0, nullptr, iM0, 0.f, w01, nullptr,
        nullptr, nullptr, nullptr, nullptr, nullptr, hA0, st + 4096,
        4096, 0, 0, hA1, st + 16384, iM1, w11, nullptr, hA1, st + 20480);
    // ---- merged L3 (pool) ----
    mlp_gemm<128, 64, 1, 16, true, false, true><<<12288, 256, 0, stream>>>(
        hA0, nullptr, st + 4096, nullptr, iM0, 0.f, w02, nullptr,
        nullptr, nullptr, nullptr, nullptr, nullptr, pool0, st + 8192,
        4096, 4, 5, hA1, st + 20480, iM1, w12, nullptr, pool1, st + 24576);
  } else {
    // ---- r16 serial path (shared hA, proven) ----
    mlp_gemm<64, 67, 0, 16, false, false, false><<<4096, 256, 0, stream>>>(
        nullptr, nullptr, nullptr, nullptr, 0.f, 0.f, w00, nullptr,
        idx0, xyz, nxyz, feats, nullptr, hA0, st + 0, NOMERGE);
    mlp_gemm<64, 64, 1, 1, false, false, false><<<4096, 256, 0, stream>>>(
        hA0, nullptr, st + 0, nullptr, iM0, 0.f, w01, nullptr,
        nullptr, nullptr, nullptr, nullptr, nullptr, hA0, st + 4096, NOMERGE);
    mlp_gemm<128, 64, 1, 16, true, false, false><<<4096, 256, 0, stream>>>(
        hA0, nullptr, st + 4096, nullptr, iM0, 0.f, w02, nullptr,
        nullptr, nullptr, nullptr, nullptr, nullptr, pool0, st + 8192, NOMERGE);
    mlp_gemm<64, 67, 0, 32, false, false, false><<<8192, 256, 0, stream>>>(
        nullptr, nullptr, nullptr, nullptr, 0.f, 0.f, w10, nullptr,
        idx1, xyz, nxyz, feats, nullptr, hA1, st + 16384, NOMERGE);
    mlp_gemm<64, 64, 1, 1, false, false, false><<<8192, 256, 0, stream>>>(
        hA1, nullptr, st + 16384, nullptr, iM1, 0.f, w11, nullptr,
        nullptr, nullptr, nullptr, nullptr, nullptr, hA1, st + 20480, NOMERGE);
    mlp_gemm<128, 64, 1, 32, true, false, false><<<8192, 256, 0, stream>>>(
        hA1, nullptr, st + 20480, nullptr, iM1, 0.f, w12, nullptr,
        nullptr, nullptr, nullptr, nullptr, nullptr, pool1, st + 24576, NOMERGE);
  }

  // ---- aggregation: concat(bn3_0(pool0), bn3_1(pool1)) @ agg_w + agg_b ----
  mlp_gemm<256, 256, 2, 1, false, true, false><<<256, 256, 0, stream>>>(
      pool0, pool1, st + 8192, st + 24576, iM0, iM1, aggw, aggb,
      nullptr, nullptr, nullptr, nullptr, nullptr, aggraw, st + 32768, NOMERGE);

  // ---- confidence hidden layer (MODE 4: bn+relu(aggraw) -> h to d_out) ----
  mlp_gemm<256, 256, 4, 1, false, false, false><<<256, 256, 0, stream>>>(
      aggraw, nullptr, st + 32768, nullptr, iMh, 0.f, confw, nullptr,
      nullptr, nullptr, nullptr, nullptr, hout, confraw, st + 49152, NOMERGE);

  // ---- classifier ----
  cls_kernel<<<BS / 4, 256, 0, stream>>>(confraw, st + 49152, clsw, clsb, clsout);
}